// Round 1
// baseline (29.397 us; speedup 1.0000x reference)
//
#include <hip/hip_runtime.h>
#include <math.h>
#include <stdint.h>

// MMCE: sum_{i,j} (c_i - p_i)(c_j - p_j) * exp(-|p_i - p_j| / 0.4) / N^2
// where p_i = max softmax prob of row i, c_i = (argmax_i == target_i).
//
// Decomposition: for p_i >= p_j, exp(-(p_i-p_j)/bw) = e^{-p_i/bw} * e^{+p_j/bw}.
// Precompute a_i = v_i * e^{-p_i/bw}, b_i = v_i * e^{+p_i/bw}  (v_i = c_i - p_i).
// Pair term = (p_i >= p_j) ? a_i*b_j : b_i*a_j.   (consistent at equality)
// p in (0,1] so e^{p/0.4} <= e^{2.5} ~ 12.2: no overflow; each term |.| <= 1.

#define WAVE 64
static constexpr float KBW_INV = 2.5f;  // 1/0.4

// ---------------- Kernel 1: per-row softmax-max stats (1 wave per row) ----
__global__ __launch_bounds__(256) void rowstats_kernel(
    const float* __restrict__ inp, const int* __restrict__ tgt,
    float* __restrict__ P, float* __restrict__ A, float* __restrict__ B,
    int N, int C) {
  const int wave = threadIdx.x >> 6;
  const int lane = threadIdx.x & 63;
  const int row = blockIdx.x * 4 + wave;
  if (row >= N) return;
  const int C4 = C >> 2;  // C == 1000 -> 250 float4 per row (C % 4 == 0)
  const float4* rp = reinterpret_cast<const float4*>(inp + (size_t)row * C);

  // Load whole row into registers: up to 4 float4 per lane.
  float4 x[4];
  bool valid[4];
  float m = -INFINITY;
  int am = 0x7fffffff;
  #pragma unroll
  for (int w = 0; w < 4; ++w) {
    const int k = lane + w * WAVE;
    valid[w] = (k < C4);
    if (valid[w]) {
      float4 v = rp[k];
      x[w] = v;
      const int base = k * 4;
      // increasing index order within lane + strict '>' keeps first occurrence
      if (v.x > m) { m = v.x; am = base + 0; }
      if (v.y > m) { m = v.y; am = base + 1; }
      if (v.z > m) { m = v.z; am = base + 2; }
      if (v.w > m) { m = v.w; am = base + 3; }
    }
  }
  // Wave reduce (max, argmax) with first-index tie-break.
  #pragma unroll
  for (int off = 32; off; off >>= 1) {
    float om = __shfl_xor(m, off);
    int oi = __shfl_xor(am, off);
    if (om > m || (om == m && oi < am)) { m = om; am = oi; }
  }
  // Sum of exp(x - m) over the row.
  float s = 0.f;
  #pragma unroll
  for (int w = 0; w < 4; ++w) {
    if (valid[w]) {
      s += __expf(x[w].x - m) + __expf(x[w].y - m) +
           __expf(x[w].z - m) + __expf(x[w].w - m);
    }
  }
  #pragma unroll
  for (int off = 32; off; off >>= 1) s += __shfl_xor(s, off);

  if (lane == 0) {
    const float p = 1.0f / s;                       // max softmax prob
    const float v = ((tgt[row] == am) ? 1.0f : 0.0f) - p;
    P[row] = p;
    A[row] = v * __expf(-p * KBW_INV);
    B[row] = v * __expf(p * KBW_INV);
  }
}

// ---------------- Kernel 2: pairwise sum over (i,j) tiles -----------------
#define JBLK 256

__global__ __launch_bounds__(256) void pairwise_kernel(
    const float* __restrict__ P, const float* __restrict__ A,
    const float* __restrict__ B, double* __restrict__ partials, int N) {
  __shared__ float sp[JBLK], sa[JBLK], sb[JBLK];
  const int nIB = N / 256;
  const int bi = blockIdx.x % nIB;
  const int bj = blockIdx.x / nIB;
  const int tid = threadIdx.x;

  const int j = bj * JBLK + tid;
  sp[tid] = P[j];
  sa[tid] = A[j];
  sb[tid] = B[j];
  __syncthreads();

  const int i = bi * 256 + tid;
  const float pi = P[i];
  const float ai = A[i];
  const float bi_ = B[i];
  double acc = 0.0;
  #pragma unroll 8
  for (int t = 0; t < JBLK; ++t) {
    const float pj = sp[t];            // uniform t -> LDS broadcast
    const bool c = (pi >= pj);
    const float xx = c ? ai : bi_;
    const float yy = c ? sb[t] : sa[t];
    acc += (double)(xx * yy);
  }
  // Deterministic block reduction.
  #pragma unroll
  for (int off = 32; off; off >>= 1) acc += __shfl_xor(acc, off);
  __shared__ double wsum[4];
  if ((tid & 63) == 0) wsum[tid >> 6] = acc;
  __syncthreads();
  if (tid == 0) partials[blockIdx.x] = (wsum[0] + wsum[1]) + (wsum[2] + wsum[3]);
}

// ---------------- Kernel 3: final deterministic reduction -----------------
__global__ __launch_bounds__(256) void finalize_kernel(
    const double* __restrict__ partials, int nPart, float* __restrict__ out,
    double invN2) {
  double acc = 0.0;
  for (int k = threadIdx.x; k < nPart; k += 256) acc += partials[k];
  #pragma unroll
  for (int off = 32; off; off >>= 1) acc += __shfl_xor(acc, off);
  __shared__ double wsum[4];
  if ((threadIdx.x & 63) == 0) wsum[threadIdx.x >> 6] = acc;
  __syncthreads();
  if (threadIdx.x == 0)
    out[0] = (float)(((wsum[0] + wsum[1]) + (wsum[2] + wsum[3])) * invN2);
}

extern "C" void kernel_launch(void* const* d_in, const int* in_sizes, int n_in,
                              void* d_out, int out_size, void* d_ws, size_t ws_size,
                              hipStream_t stream) {
  const float* inp = (const float*)d_in[0];
  const int* tgt = (const int*)d_in[1];
  const int N = in_sizes[1];             // 8192
  const int C = in_sizes[0] / N;         // 1000

  float* P = (float*)d_ws;
  float* A = P + N;
  float* B = A + N;
  double* partials =
      (double*)(((uintptr_t)(B + N) + 15) & ~(uintptr_t)15);

  const int rowBlocks = (N + 3) / 4;     // 4 waves/block, 1 row/wave
  rowstats_kernel<<<rowBlocks, 256, 0, stream>>>(inp, tgt, P, A, B, N, C);

  const int nIB = N / 256;               // 32
  const int nPart = nIB * nIB;           // 1024 blocks
  pairwise_kernel<<<nPart, 256, 0, stream>>>(P, A, B, partials, N);

  finalize_kernel<<<1, 256, 0, stream>>>(partials, nPart, (float*)d_out,
                                         1.0 / ((double)N * (double)N));
}